// Round 1
// baseline (342.443 us; speedup 1.0000x reference)
//
#include <hip/hip_runtime.h>

#define EMBED_D 128   // EMBED_DIM in the reference; row = 64 float2 per lane-slice

// lower_bound over sorted tree_ids: first index i with a[i] >= v
__device__ __forceinline__ int lb(const int* __restrict__ a, int n, int v) {
    int lo = 0, hi = n;
    while (lo < hi) {
        int mid = (lo + hi) >> 1;
        if (a[mid] < v) lo = mid + 1; else hi = mid;
    }
    return lo;
}

extern "C" __global__ __launch_bounds__(256, 4)
void seg_embed_sum(const int* __restrict__ token_ids,
                   const int* __restrict__ tree_ids,
                   const float* __restrict__ Ck,
                   const float* __restrict__ Cv,
                   float* __restrict__ out,   // [2, n_seg, 128] flat
                   int n_tok, int n_seg)
{
    const int wavesPerBlock = blockDim.x >> 6;
    const int wave = blockIdx.x * wavesPerBlock + ((int)threadIdx.x >> 6);
    if (wave >= n_seg) return;
    const int lane = (int)threadIdx.x & 63;
    const int seg = wave;

    // contiguous token run for this segment (tree_ids is sorted)
    int start = lb(tree_ids, n_tok, seg);
    int end   = lb(tree_ids, n_tok, seg + 1);
    // values are wave-uniform; put them in SGPRs
    start = __builtin_amdgcn_readfirstlane(start);
    end   = __builtin_amdgcn_readfirstlane(end);

    const float2* __restrict__ K2 = (const float2*)Ck;
    const float2* __restrict__ V2 = (const float2*)Cv;

    float ka0 = 0.f, ka1 = 0.f, va0 = 0.f, va1 = 0.f;

    int i = start;
    // 4-token unroll: 8 independent dwordx2 loads in flight per wave
    for (; i + 4 <= end; i += 4) {
        const int t0 = __builtin_amdgcn_readfirstlane(token_ids[i]);
        const int t1 = __builtin_amdgcn_readfirstlane(token_ids[i + 1]);
        const int t2 = __builtin_amdgcn_readfirstlane(token_ids[i + 2]);
        const int t3 = __builtin_amdgcn_readfirstlane(token_ids[i + 3]);
        const float2 k0 = K2[(size_t)t0 * 64 + lane];
        const float2 k1 = K2[(size_t)t1 * 64 + lane];
        const float2 k2 = K2[(size_t)t2 * 64 + lane];
        const float2 k3 = K2[(size_t)t3 * 64 + lane];
        const float2 v0 = V2[(size_t)t0 * 64 + lane];
        const float2 v1 = V2[(size_t)t1 * 64 + lane];
        const float2 v2 = V2[(size_t)t2 * 64 + lane];
        const float2 v3 = V2[(size_t)t3 * 64 + lane];
        ka0 += k0.x + k1.x + k2.x + k3.x;
        ka1 += k0.y + k1.y + k2.y + k3.y;
        va0 += v0.x + v1.x + v2.x + v3.x;
        va1 += v0.y + v1.y + v2.y + v3.y;
    }
    for (; i < end; ++i) {
        const int t = __builtin_amdgcn_readfirstlane(token_ids[i]);
        const float2 k = K2[(size_t)t * 64 + lane];
        const float2 v = V2[(size_t)t * 64 + lane];
        ka0 += k.x; ka1 += k.y; va0 += v.x; va1 += v.y;
    }

    // write key ([0, seg, :]) and val ([1, seg, :]); empty segments write zeros
    float2* outv = (float2*)out;
    float2 kk; kk.x = ka0; kk.y = ka1;
    float2 vv; vv.x = va0; vv.y = va1;
    outv[(size_t)seg * 64 + lane] = kk;
    outv[(size_t)(n_seg + seg) * 64 + lane] = vv;
}

extern "C" void kernel_launch(void* const* d_in, const int* in_sizes, int n_in,
                              void* d_out, int out_size, void* d_ws, size_t ws_size,
                              hipStream_t stream) {
    const int*   token_ids = (const int*)d_in[0];
    const int*   tree_ids  = (const int*)d_in[1];
    const float* Ck        = (const float*)d_in[2];
    const float* Cv        = (const float*)d_in[3];
    float*       out       = (float*)d_out;

    const int n_tok = in_sizes[0];
    const int n_seg = out_size / (2 * EMBED_D);   // out = [2, n_seg, 128]

    const int wavesPerBlock = 4;                  // 256 threads = 4 waves, 1 seg each
    const int blocks = (n_seg + wavesPerBlock - 1) / wavesPerBlock;
    seg_embed_sum<<<blocks, 256, 0, stream>>>(token_ids, tree_ids, Ck, Cv, out,
                                              n_tok, n_seg);
}

// Round 3
// 213.506 us; speedup vs baseline: 1.6039x; 1.6039x over previous
//
#include <hip/hip_runtime.h>

#define VOCAB 32000
#define EMBED_D 128
#define TBL_ELEMS (VOCAB * EMBED_D)   // 4,096,000 elements per table

typedef unsigned short ushort;
typedef ushort ushort8 __attribute__((ext_vector_type(8)));
typedef ushort ushort4v __attribute__((ext_vector_type(4)));

__device__ __forceinline__ float bf2f(ushort u) {
    union { unsigned int i; float f; } c;
    c.i = ((unsigned int)u) << 16;
    return c.f;
}

__device__ __forceinline__ ushort f2bf(float f) {
    union { float f; unsigned int i; } c;
    c.f = f;
    unsigned int r = c.i + 0x7fffu + ((c.i >> 16) & 1u);  // RNE
    return (ushort)(r >> 16);
}

// ---- Kernel A: fp32 table -> bf16 table in workspace (vectorized x4) ----
extern "C" __global__ __launch_bounds__(256)
void cvt_bf16(const float* __restrict__ src, ushort* __restrict__ dst, int n4) {
    int idx = blockIdx.x * blockDim.x + threadIdx.x;
    int stride = gridDim.x * blockDim.x;
    const float4* s4 = (const float4*)src;
    ushort4v* d4 = (ushort4v*)dst;
    for (int i = idx; i < n4; i += stride) {
        float4 v = s4[i];
        ushort4v o;
        o[0] = f2bf(v.x); o[1] = f2bf(v.y); o[2] = f2bf(v.z); o[3] = f2bf(v.w);
        d4[i] = o;
    }
}

// ---- Kernel B: per-segment token-run boundaries (tree_ids is sorted) ----
extern "C" __global__ __launch_bounds__(256)
void seg_bounds(const int* __restrict__ tree_ids, int* __restrict__ bounds,
                int n_tok, int n_seg) {
    int s = blockIdx.x * blockDim.x + threadIdx.x;
    if (s > n_seg) return;
    int lo = 0, hi = n_tok;
    while (lo < hi) {
        int mid = (lo + hi) >> 1;
        if (tree_ids[mid] < s) lo = mid + 1; else hi = mid;
    }
    bounds[s] = lo;
}

// ---- Kernel C: one wave per segment; 4 tokens per dwordx4 row-load ----
extern "C" __global__ __launch_bounds__(256, 4)
void seg_embed_sum_bf16(const int* __restrict__ token_ids,
                        const int* __restrict__ bounds,
                        const ushort* __restrict__ Kb,
                        const ushort* __restrict__ Vb,
                        float* __restrict__ out,   // [2, n_seg, 128]
                        int n_seg)
{
    const int wave = blockIdx.x * (blockDim.x >> 6) + ((int)threadIdx.x >> 6);
    if (wave >= n_seg) return;
    const int lane = (int)threadIdx.x & 63;
    const int g = lane >> 4;          // lane group: which token of 4
    const int s = lane & 15;          // 8-elem slice of the 128-dim row

    int start = __builtin_amdgcn_readfirstlane(bounds[wave]);
    int end   = __builtin_amdgcn_readfirstlane(bounds[wave + 1]);

    float ka[8] = {0.f,0.f,0.f,0.f,0.f,0.f,0.f,0.f};
    float va[8] = {0.f,0.f,0.f,0.f,0.f,0.f,0.f,0.f};

    int i = start;
    // main loop: 16 tokens/iter -> 8 x 1KB row-loads in flight per wave
    for (; i + 16 <= end; i += 16) {
        const int i0 = i + 2 * g;
        const int t0 = token_ids[i0];
        const int t1 = token_ids[i0 + 1];
        const int t2 = token_ids[i0 + 8];
        const int t3 = token_ids[i0 + 9];
        const ushort8 k0 = *(const ushort8*)(Kb + (size_t)t0 * EMBED_D + s * 8);
        const ushort8 k1 = *(const ushort8*)(Kb + (size_t)t1 * EMBED_D + s * 8);
        const ushort8 k2 = *(const ushort8*)(Kb + (size_t)t2 * EMBED_D + s * 8);
        const ushort8 k3 = *(const ushort8*)(Kb + (size_t)t3 * EMBED_D + s * 8);
        const ushort8 v0 = *(const ushort8*)(Vb + (size_t)t0 * EMBED_D + s * 8);
        const ushort8 v1 = *(const ushort8*)(Vb + (size_t)t1 * EMBED_D + s * 8);
        const ushort8 v2 = *(const ushort8*)(Vb + (size_t)t2 * EMBED_D + s * 8);
        const ushort8 v3 = *(const ushort8*)(Vb + (size_t)t3 * EMBED_D + s * 8);
        #pragma unroll
        for (int e = 0; e < 8; ++e) {
            ka[e] += (bf2f(k0[e]) + bf2f(k1[e])) + (bf2f(k2[e]) + bf2f(k3[e]));
            va[e] += (bf2f(v0[e]) + bf2f(v1[e])) + (bf2f(v2[e]) + bf2f(v3[e]));
        }
    }
    // tail: 8 tokens/iter, OOB tokens -> PAD(0), whose row is all zeros
    for (; i < end; i += 8) {
        const int i0 = i + 2 * g;
        const int t0 = (i0     < end) ? token_ids[i0]     : 0;
        const int t1 = (i0 + 1 < end) ? token_ids[i0 + 1] : 0;
        const ushort8 k0 = *(const ushort8*)(Kb + (size_t)t0 * EMBED_D + s * 8);
        const ushort8 k1 = *(const ushort8*)(Kb + (size_t)t1 * EMBED_D + s * 8);
        const ushort8 v0 = *(const ushort8*)(Vb + (size_t)t0 * EMBED_D + s * 8);
        const ushort8 v1 = *(const ushort8*)(Vb + (size_t)t1 * EMBED_D + s * 8);
        #pragma unroll
        for (int e = 0; e < 8; ++e) {
            ka[e] += bf2f(k0[e]) + bf2f(k1[e]);
            va[e] += bf2f(v0[e]) + bf2f(v1[e]);
        }
    }

    // reduce across the 4 lane-groups (butterfly over lane bits 4,5)
    #pragma unroll
    for (int e = 0; e < 8; ++e) {
        ka[e] += __shfl_xor(ka[e], 16, 64);
        ka[e] += __shfl_xor(ka[e], 32, 64);
        va[e] += __shfl_xor(va[e], 16, 64);
        va[e] += __shfl_xor(va[e], 32, 64);
    }

    if (g == 0) {            // K row: out[0, wave, :]
        float4* dst = (float4*)(out + (size_t)wave * EMBED_D + s * 8);
        float4 a; a.x = ka[0]; a.y = ka[1]; a.z = ka[2]; a.w = ka[3];
        float4 b; b.x = ka[4]; b.y = ka[5]; b.z = ka[6]; b.w = ka[7];
        dst[0] = a; dst[1] = b;
    } else if (g == 1) {     // V row: out[1, wave, :]
        float4* dst = (float4*)(out + (size_t)(n_seg + wave) * EMBED_D + s * 8);
        float4 a; a.x = va[0]; a.y = va[1]; a.z = va[2]; a.w = va[3];
        float4 b; b.x = va[4]; b.y = va[5]; b.z = va[6]; b.w = va[7];
        dst[0] = a; dst[1] = b;
    }
}

// ---- Fallback (R1 fp32 path) in case ws is too small ----
__device__ __forceinline__ int lb(const int* __restrict__ a, int n, int v) {
    int lo = 0, hi = n;
    while (lo < hi) {
        int mid = (lo + hi) >> 1;
        if (a[mid] < v) lo = mid + 1; else hi = mid;
    }
    return lo;
}

extern "C" __global__ __launch_bounds__(256, 4)
void seg_embed_sum_f32(const int* __restrict__ token_ids,
                       const int* __restrict__ tree_ids,
                       const float* __restrict__ Ck,
                       const float* __restrict__ Cv,
                       float* __restrict__ out, int n_tok, int n_seg)
{
    const int wave = blockIdx.x * (blockDim.x >> 6) + ((int)threadIdx.x >> 6);
    if (wave >= n_seg) return;
    const int lane = (int)threadIdx.x & 63;
    int start = __builtin_amdgcn_readfirstlane(lb(tree_ids, n_tok, wave));
    int end   = __builtin_amdgcn_readfirstlane(lb(tree_ids, n_tok, wave + 1));
    const float2* K2 = (const float2*)Ck;
    const float2* V2 = (const float2*)Cv;
    float ka0 = 0.f, ka1 = 0.f, va0 = 0.f, va1 = 0.f;
    for (int i = start; i < end; ++i) {
        const int t = __builtin_amdgcn_readfirstlane(token_ids[i]);
        const float2 k = K2[(size_t)t * 64 + lane];
        const float2 v = V2[(size_t)t * 64 + lane];
        ka0 += k.x; ka1 += k.y; va0 += v.x; va1 += v.y;
    }
    float2* outv = (float2*)out;
    float2 kk; kk.x = ka0; kk.y = ka1;
    float2 vv; vv.x = va0; vv.y = va1;
    outv[(size_t)wave * 64 + lane] = kk;
    outv[(size_t)(n_seg + wave) * 64 + lane] = vv;
}

extern "C" void kernel_launch(void* const* d_in, const int* in_sizes, int n_in,
                              void* d_out, int out_size, void* d_ws, size_t ws_size,
                              hipStream_t stream) {
    const int*   token_ids = (const int*)d_in[0];
    const int*   tree_ids  = (const int*)d_in[1];
    const float* Ck        = (const float*)d_in[2];
    const float* Cv        = (const float*)d_in[3];
    float*       out       = (float*)d_out;

    const int n_tok = in_sizes[0];
    const int n_seg = out_size / (2 * EMBED_D);   // out = [2, n_seg, 128]

    const size_t need = (size_t)TBL_ELEMS * 2 * sizeof(ushort) + (size_t)(n_seg + 1) * sizeof(int);
    if (ws_size < need) {  // fallback: R1 fp32 path
        const int blocks = (n_seg + 3) / 4;
        seg_embed_sum_f32<<<blocks, 256, 0, stream>>>(token_ids, tree_ids, Ck, Cv,
                                                      out, n_tok, n_seg);
        return;
    }

    ushort* Kb = (ushort*)d_ws;
    ushort* Vb = Kb + TBL_ELEMS;
    int* bounds = (int*)(Vb + TBL_ELEMS);

    cvt_bf16<<<2048, 256, 0, stream>>>(Ck, Kb, TBL_ELEMS / 4);
    cvt_bf16<<<2048, 256, 0, stream>>>(Cv, Vb, TBL_ELEMS / 4);
    seg_bounds<<<(n_seg + 1 + 255) / 256, 256, 0, stream>>>(tree_ids, bounds, n_tok, n_seg);

    const int blocks = (n_seg + 3) / 4;   // 4 waves/block, 1 segment/wave
    seg_embed_sum_bf16<<<blocks, 256, 0, stream>>>(token_ids, bounds, Kb, Vb,
                                                   out, n_seg);
}

// Round 4
// 193.133 us; speedup vs baseline: 1.7731x; 1.1055x over previous
//
#include <hip/hip_runtime.h>

#define VOCAB 32000
#define EMBED_D 128
#define TBL_ELEMS (VOCAB * EMBED_D)   // 4,096,000 elements per table

// ---------------------------------------------------------------- helpers
__device__ __forceinline__ float wave_max64(float m) {
    #pragma unroll
    for (int d = 1; d < 64; d <<= 1) m = fmaxf(m, __shfl_xor(m, d, 64));
    return m;
}

// unpack 16 int8 (int4 = 4 dwords) and accumulate acc[e] += q[e] * s
__device__ __forceinline__ void unpack_acc(const int4 r, const float s, float* acc) {
    const int w0 = r.x, w1 = r.y, w2 = r.z, w3 = r.w;
    const int w[4] = {w0, w1, w2, w3};
    #pragma unroll
    for (int k = 0; k < 4; ++k) {
        #pragma unroll
        for (int b = 0; b < 4; ++b) {
            const int q = __builtin_amdgcn_sbfe(w[k], 8 * b, 8);  // v_bfe_i32
            acc[k * 4 + b] = fmaf((float)q, s, acc[k * 4 + b]);
        }
    }
}

// ---- Kernel A: fp32 tables -> int8 rows + per-row fp32 scale -------------
// one wave per row; waves [0,VOCAB) = K table, [VOCAB,2*VOCAB) = V table
extern "C" __global__ __launch_bounds__(256)
void quant_i8(const float* __restrict__ Ck, const float* __restrict__ Cv,
              char* __restrict__ Kq, char* __restrict__ Vq,
              float* __restrict__ sK, float* __restrict__ sV)
{
    const int wave = blockIdx.x * 4 + ((int)threadIdx.x >> 6);
    if (wave >= 2 * VOCAB) return;
    const int lane = (int)threadIdx.x & 63;
    const bool isV = wave >= VOCAB;
    const int row = isV ? wave - VOCAB : wave;

    const float* src = (isV ? Cv : Ck) + (size_t)row * EMBED_D;
    char*       dst = (isV ? Vq : Kq) + (size_t)row * EMBED_D;

    const float2 v = ((const float2*)src)[lane];
    float m = fmaxf(fabsf(v.x), fabsf(v.y));
    m = wave_max64(m);

    const float inv = (m > 0.f) ? 127.f / m : 0.f;
    int q0 = (int)rintf(v.x * inv);
    int q1 = (int)rintf(v.y * inv);
    q0 = q0 < -127 ? -127 : (q0 > 127 ? 127 : q0);
    q1 = q1 < -127 ? -127 : (q1 > 127 ? 127 : q1);

    char2 p; p.x = (char)q0; p.y = (char)q1;
    ((char2*)dst)[lane] = p;
    if (lane == 0) (isV ? sV : sK)[row] = m * (1.f / 127.f);  // 0 for pad row
}

// ---- Kernel B: per-segment token-run boundaries (tree_ids sorted) -------
extern "C" __global__ __launch_bounds__(256)
void seg_bounds(const int* __restrict__ tree_ids, int* __restrict__ bounds,
                int n_tok, int n_seg) {
    int s = blockIdx.x * blockDim.x + threadIdx.x;
    if (s > n_seg) return;
    int lo = 0, hi = n_tok;
    while (lo < hi) {
        int mid = (lo + hi) >> 1;
        if (tree_ids[mid] < s) lo = mid + 1; else hi = mid;
    }
    bounds[s] = lo;
}

// ---- Kernel C: one wave per segment; int8 rows, 8 tokens / dwordx4 ------
// lane layout: g = lane>>3 (token slot 0..7), s = lane&7 (16-elem slice)
extern "C" __global__ __launch_bounds__(256, 4)
void seg_embed_sum_i8(const int* __restrict__ token_ids,
                      const int* __restrict__ bounds,
                      const char* __restrict__ Kq,
                      const char* __restrict__ Vq,
                      const float* __restrict__ sK,
                      const float* __restrict__ sV,
                      float* __restrict__ out,   // [2, n_seg, 128]
                      int n_seg)
{
    const int wave = blockIdx.x * (blockDim.x >> 6) + ((int)threadIdx.x >> 6);
    if (wave >= n_seg) return;
    const int lane = (int)threadIdx.x & 63;
    const int g = lane >> 3;
    const int byteoff = (lane & 7) * 16;

    int start = __builtin_amdgcn_readfirstlane(bounds[wave]);
    int end   = __builtin_amdgcn_readfirstlane(bounds[wave + 1]);

    float accK[16], accV[16];
    #pragma unroll
    for (int e = 0; e < 16; ++e) { accK[e] = 0.f; accV[e] = 0.f; }

    int i = start;
    // main loop: 32 tokens/iter -> 8 row-loads (dwordx4) in flight per wave
    for (; i + 32 <= end; i += 32) {
        int t4[4]; float k4[4], v4[4]; int4 rk4[4], rv4[4];
        #pragma unroll
        for (int j = 0; j < 4; ++j) t4[j] = token_ids[i + 8 * j + g];
        #pragma unroll
        for (int j = 0; j < 4; ++j) {
            k4[j] = sK[t4[j]];
            v4[j] = sV[t4[j]];
            rk4[j] = *(const int4*)(Kq + (size_t)t4[j] * EMBED_D + byteoff);
            rv4[j] = *(const int4*)(Vq + (size_t)t4[j] * EMBED_D + byteoff);
        }
        #pragma unroll
        for (int j = 0; j < 4; ++j) {
            unpack_acc(rk4[j], k4[j], accK);
            unpack_acc(rv4[j], v4[j], accV);
        }
    }
    // tail: 8 tokens/iter; OOB slots -> token 0 (pad row, scale 0 -> adds 0)
    for (; i < end; i += 8) {
        const int idx = i + g;
        const int t = (idx < end) ? token_ids[idx] : 0;
        const float skv = sK[t];
        const float svv = sV[t];
        const int4 rk = *(const int4*)(Kq + (size_t)t * EMBED_D + byteoff);
        const int4 rv = *(const int4*)(Vq + (size_t)t * EMBED_D + byteoff);
        unpack_acc(rk, skv, accK);
        unpack_acc(rv, svv, accV);
    }

    // reduce across the 8 token slots (butterfly over lane bits 3,4,5)
    #pragma unroll
    for (int e = 0; e < 16; ++e) {
        accK[e] += __shfl_xor(accK[e], 8, 64);
        accK[e] += __shfl_xor(accK[e], 16, 64);
        accK[e] += __shfl_xor(accK[e], 32, 64);
        accV[e] += __shfl_xor(accV[e], 8, 64);
        accV[e] += __shfl_xor(accV[e], 16, 64);
        accV[e] += __shfl_xor(accV[e], 32, 64);
    }

    const int s16 = (lane & 7) * 16;
    if (g == 0) {            // K row: out[0, wave, :]
        float4* dst = (float4*)(out + (size_t)wave * EMBED_D + s16);
        #pragma unroll
        for (int q = 0; q < 4; ++q) {
            float4 o; o.x = accK[q*4]; o.y = accK[q*4+1]; o.z = accK[q*4+2]; o.w = accK[q*4+3];
            dst[q] = o;
        }
    } else if (g == 1) {     // V row: out[1, wave, :]
        float4* dst = (float4*)(out + (size_t)(n_seg + wave) * EMBED_D + s16);
        #pragma unroll
        for (int q = 0; q < 4; ++q) {
            float4 o; o.x = accV[q*4]; o.y = accV[q*4+1]; o.z = accV[q*4+2]; o.w = accV[q*4+3];
            dst[q] = o;
        }
    }
}

// ---- Fallback (R1 fp32 path) in case ws is too small --------------------
__device__ __forceinline__ int lb(const int* __restrict__ a, int n, int v) {
    int lo = 0, hi = n;
    while (lo < hi) {
        int mid = (lo + hi) >> 1;
        if (a[mid] < v) lo = mid + 1; else hi = mid;
    }
    return lo;
}

extern "C" __global__ __launch_bounds__(256, 4)
void seg_embed_sum_f32(const int* __restrict__ token_ids,
                       const int* __restrict__ tree_ids,
                       const float* __restrict__ Ck,
                       const float* __restrict__ Cv,
                       float* __restrict__ out, int n_tok, int n_seg)
{
    const int wave = blockIdx.x * (blockDim.x >> 6) + ((int)threadIdx.x >> 6);
    if (wave >= n_seg) return;
    const int lane = (int)threadIdx.x & 63;
    int start = __builtin_amdgcn_readfirstlane(lb(tree_ids, n_tok, wave));
    int end   = __builtin_amdgcn_readfirstlane(lb(tree_ids, n_tok, wave + 1));
    const float2* K2 = (const float2*)Ck;
    const float2* V2 = (const float2*)Cv;
    float ka0 = 0.f, ka1 = 0.f, va0 = 0.f, va1 = 0.f;
    for (int i = start; i < end; ++i) {
        const int t = __builtin_amdgcn_readfirstlane(token_ids[i]);
        const float2 k = K2[(size_t)t * 64 + lane];
        const float2 v = V2[(size_t)t * 64 + lane];
        ka0 += k.x; ka1 += k.y; va0 += v.x; va1 += v.y;
    }
    float2* outv = (float2*)out;
    float2 kk; kk.x = ka0; kk.y = ka1;
    float2 vv; vv.x = va0; vv.y = va1;
    outv[(size_t)wave * 64 + lane] = kk;
    outv[(size_t)(n_seg + wave) * 64 + lane] = vv;
}

extern "C" void kernel_launch(void* const* d_in, const int* in_sizes, int n_in,
                              void* d_out, int out_size, void* d_ws, size_t ws_size,
                              hipStream_t stream) {
    const int*   token_ids = (const int*)d_in[0];
    const int*   tree_ids  = (const int*)d_in[1];
    const float* Ck        = (const float*)d_in[2];
    const float* Cv        = (const float*)d_in[3];
    float*       out       = (float*)d_out;

    const int n_tok = in_sizes[0];
    const int n_seg = out_size / (2 * EMBED_D);   // out = [2, n_seg, 128]

    const size_t need = (size_t)TBL_ELEMS * 2          // int8 tables
                      + (size_t)VOCAB * 2 * sizeof(float)   // scales
                      + (size_t)(n_seg + 1) * sizeof(int);  // bounds
    if (ws_size < need) {  // fallback: fp32 direct path
        const int blocks = (n_seg + 3) / 4;
        seg_embed_sum_f32<<<blocks, 256, 0, stream>>>(token_ids, tree_ids, Ck, Cv,
                                                      out, n_tok, n_seg);
        return;
    }

    char*  Kq = (char*)d_ws;
    char*  Vq = Kq + TBL_ELEMS;
    float* sK = (float*)(Vq + TBL_ELEMS);
    float* sV = sK + VOCAB;
    int*   bounds = (int*)(sV + VOCAB);

    quant_i8<<<(2 * VOCAB + 3) / 4, 256, 0, stream>>>(Ck, Cv, Kq, Vq, sK, sV);
    seg_bounds<<<(n_seg + 1 + 255) / 256, 256, 0, stream>>>(tree_ids, bounds, n_tok, n_seg);

    const int blocks = (n_seg + 3) / 4;   // 4 waves/block, 1 segment/wave
    seg_embed_sum_i8<<<blocks, 256, 0, stream>>>(token_ids, bounds, Kq, Vq,
                                                 sK, sV, out, n_seg);
}